// Round 14
// baseline (216.577 us; speedup 1.0000x reference)
//
#include <hip/hip_runtime.h>
#include <hip/hip_bf16.h>

#define NN 50000      // nodes
#define NE 800000     // edges
#define NR 20         // relations
#define NB 8          // bases
#define D  128        // hidden dim
#define DO 64         // output dim
#define NT 782        // ceil(NN/64) dst tiles
#define NBKT (NT*1280) // (tile, rel, dl) buckets = 1,000,960
#define NSB 978       // ceil(NBKT/1024)

typedef __attribute__((ext_vector_type(8))) short short8;
typedef __attribute__((ext_vector_type(4))) float f32x4;

__device__ inline unsigned short f2bf(float f) {
    __hip_bfloat16 h = __float2bfloat16(f);
    return *reinterpret_cast<unsigned short*>(&h);
}
__device__ inline float bf2f(unsigned short u) {
    unsigned x = ((unsigned)u) << 16;
    float f;
    __builtin_memcpy(&f, &x, 4);
    return f;
}

// ---------------------------------------------------------------------------
// ws layout (bytes):
//   [0        ..  4,003,840) cnt2    NBKT int  -- zeroed each call
//   [4,003,840..  4,007,752) bsum    NSB int   -- zeroed (rewritten by scan1)
//   [4,007,752..  4,007,756) scancnt int       -- zeroed each call
//   [4,007,808..  8,011,652) boff2   NBKT+1 int
//   [8,011,712.. 12,015,552) gcur2   NBKT int
//   [12,015,616..12,025,856) W0      NR*D f32
//   [12,025,856..12,681,216) W1b     NR*16384 bf16 (B-fragment order)
//   [12,681,216..25,481,216) h1b     NN*D bf16
//   [25,481,216..27,081,216) epack   NE ushort (src ids, sorted by (tile,r,dl))
//   [28,681,216..28,697,600) linWb   lin_w in B-fragment order, bf16
// ---------------------------------------------------------------------------

// Fused: weights build (blocks 0..39) + (tile,rel,dl) histogram (all blocks).
__global__ __launch_bounds__(1024) void k_wh(
        const float* __restrict__ basis0, const float* __restrict__ wcomp0,
        const float* __restrict__ basis1, const float* __restrict__ wcomp1,
        const float* __restrict__ lin_w,
        const int* __restrict__ dst, const int* __restrict__ et,
        float* __restrict__ W0, unsigned short* __restrict__ W1b,
        unsigned short* __restrict__ linWb, int* __restrict__ cnt2) {
    int idx = blockIdx.x * 1024 + threadIdx.x;
    // ---- weights part (idx < 40960) ----
    if (idx < NR * D) {
        int r = idx / D, o = idx % D;
        float a = 0.f;
        #pragma unroll
        for (int b = 0; b < NB; b++) a += wcomp0[r * NB + b] * basis0[b * D + o];
        W0[idx] = a;
    }
    if (idx < 16 * 64) {
        int lane = idx & 63, fr = idx >> 6;
        int kc = fr >> 2, nt = fr & 3;
        int i0 = kc * 32 + (lane >> 4) * 8;
        int o = nt * 16 + (lane & 15);
        short8 v;
        #pragma unroll
        for (int e = 0; e < 8; e++) v[e] = (short)f2bf(lin_w[(i0 + e) * DO + o]);
        *((short8*)linWb + idx) = v;
    }
    if (idx < NR * 4 * 8 * 64) {
        int lane = idx & 63;
        int cb   = (idx >> 6) & 7;
        int kc   = (idx >> 9) & 3;
        int rel  = idx >> 11;
        float wc[NB];
        #pragma unroll
        for (int b = 0; b < NB; b++) wc[b] = wcomp1[rel * NB + b];
        int o  = cb * 16 + (lane & 15);
        int i0 = kc * 32 + (lane >> 4) * 8;
        short8 v;
        #pragma unroll
        for (int e = 0; e < 8; e++) {
            int i = i0 + e;
            float a = 0.f;
            #pragma unroll
            for (int b = 0; b < NB; b++) a += wc[b] * basis1[(b * D + i) * D + o];
            v[e] = (short)f2bf(a);
        }
        *((short8*)W1b + idx) = v;
    }
    // ---- hist part ----
    if (idx < NE) {
        int d = dst[idx];
        int key = (d >> 6) * 1280 + et[idx] * 64 + (d & 63);
        atomicAdd(&cnt2[key], 1);
    }
}

// Scan phase 1 + fused phase 2 (last-finishing block scans bsum in place).
__global__ __launch_bounds__(1024) void k_scan1(const int* __restrict__ cnt2,
                                                int* __restrict__ boff2,
                                                int* __restrict__ bsum,
                                                int* __restrict__ scancnt) {
    __shared__ int ws[16];
    __shared__ int lastf;
    int t = threadIdx.x, lane = t & 63, wv = t >> 6;
    int i = blockIdx.x * 1024 + t;
    int v = (i < NBKT) ? cnt2[i] : 0;
    int inc = v;
    for (int dd = 1; dd < 64; dd <<= 1) {
        int u = __shfl_up(inc, dd);
        if (lane >= dd) inc += u;
    }
    if (lane == 63) ws[wv] = inc;
    __syncthreads();
    if (t == 0) { int a = 0; for (int j = 0; j < 16; j++) { int x = ws[j]; ws[j] = a; a += x; } }
    __syncthreads();
    int ex = ws[wv] + inc - v;
    if (i < NBKT) boff2[i] = ex;
    if (t == 1023) {
        bsum[blockIdx.x] = ex + v;
        __threadfence();
        int done = atomicAdd(scancnt, 1);
        lastf = (done == (int)gridDim.x - 1);
    }
    __syncthreads();
    if (!lastf) return;
    // ---- fused scan2: this block scans bsum (device-scope RMW reads) ----
    int v2 = (t < NSB) ? atomicAdd(&bsum[t], 0) : 0;
    int inc2 = v2;
    for (int dd = 1; dd < 64; dd <<= 1) {
        int u = __shfl_up(inc2, dd);
        if (lane >= dd) inc2 += u;
    }
    __syncthreads();
    if (lane == 63) ws[wv] = inc2;
    __syncthreads();
    if (t == 0) { int a = 0; for (int j = 0; j < 16; j++) { int x = ws[j]; ws[j] = a; a += x; } }
    __syncthreads();
    if (t < NSB) bsum[t] = ws[wv] + inc2 - v2;
}

// Fused: scan phase 3 (all 978 blocks) + h1 compute (blocks < NT).
__global__ __launch_bounds__(1024) void k_mid(
        int* __restrict__ boff2, const int* __restrict__ bsum,
        int* __restrict__ gcur2, const int* __restrict__ cnt2,
        const float* __restrict__ W0, const float* __restrict__ bias0,
        unsigned short* __restrict__ h1b) {
    __shared__ float cs[NR * 64];
    __shared__ float w0s[NR * D];
    int t = threadIdx.x, b = blockIdx.x;
    // scan3 part
    int i = b * 1024 + t;
    if (i < NBKT) {
        int f = boff2[i] + bsum[i >> 10];
        boff2[i] = f;
        gcur2[i] = f;
    }
    if (i == 0) boff2[NBKT] = NE;
    // h1 part
    if (b < NT) {
        for (int j = t; j < NR * 64; j += 1024) cs[j] = (float)cnt2[b * 1280 + j];
        for (int j = t; j < NR * D; j += 1024) w0s[j] = W0[j];
        __syncthreads();
        int nl = t >> 4, cg = t & 15;          // node-local, col-group of 8
        int n = b * 64 + nl;
        if (n < NN) {
            float a[8];
            #pragma unroll
            for (int j = 0; j < 8; j++) a[j] = bias0[cg * 8 + j];
            for (int r = 0; r < NR; r++) {
                float c = cs[r * 64 + nl];
                #pragma unroll
                for (int j = 0; j < 8; j++) a[j] += c * w0s[r * D + cg * 8 + j];
            }
            short8 o;
            #pragma unroll
            for (int j = 0; j < 8; j++) o[j] = (short)f2bf(fmaxf(a[j], 0.f));
            *((short8*)(h1b + n * D + cg * 8)) = o;
        }
    }
}

// Counting-sort scatter: epack[pos] = src (ushort), grouped by (tile,rel,dl).
__global__ __launch_bounds__(1024) void k_scatter(
        const int* __restrict__ src, const int* __restrict__ dst,
        const int* __restrict__ et, int* __restrict__ gcur2,
        unsigned short* __restrict__ epack) {
    int i = blockIdx.x * 1024 + threadIdx.x;
    if (i < NE) {
        int d = dst[i];
        int key = (d >> 6) * 1280 + et[i] * 64 + (d & 63);
        int pos = atomicAdd(&gcur2[key], 1);
        epack[pos] = (unsigned short)src[i];
    }
}

// Mega v11 (r13-proven, unchanged structure; epack now ushort):
// 512 thr / 64-dst tile; wave wv owns output cols wv*16..+15 for all 64 rows.
// Per rel: 4 B-frag register loads (reused 4x) issued at rel-top; stage 64
// rows -> Raw; reduce own bucket; publish swizzled Sl; 16 MFMA. 2 barriers/rel.
__global__ __launch_bounds__(512, 2) void k_mega(
        const unsigned short* __restrict__ epack, const int* __restrict__ boff2,
        const unsigned short* __restrict__ h1b,
        const unsigned short* __restrict__ W1b,
        const unsigned short* __restrict__ linWb,
        const float* __restrict__ bias1, const float* __restrict__ lin_b,
        float* __restrict__ out) {
    __shared__ __align__(16) char lds[17408 + 16384];  // Raw 64x17s8 | Sl 64x16s8
    __shared__ int ooff[1281];

    short8* Raw8 = (short8*)lds;
    short8* Sl8  = (short8*)(lds + 17408);

    int t = threadIdx.x, tile = blockIdx.x;
    int wv = t >> 6, lane = t & 63;
    int le = t >> 3, lp = t & 7;             // stage role: edge row, 16B pair
    int dl = t >> 3, cg = t & 7;             // reduce role: dst-local, col-group
    int row = lane & 15, gg = lane >> 4;     // mfma role

    for (int i = t; i < 1281; i += 512) ooff[i] = boff2[tile * 1280 + i];
    __syncthreads();

    f32x4 acc[4];
    #pragma unroll
    for (int j = 0; j < 4; j++) acc[j] = (f32x4){0.f, 0.f, 0.f, 0.f};

    for (int r = 0; r < NR; r++) {
        int rbase = ooff[r * 64];
        int cnt = ooff[r * 64 + 64] - rbase;     // block-uniform
        if (cnt == 0) continue;

        const short8* Wg8 = (const short8*)W1b + r * 2048;
        short8 breg[4];
        #pragma unroll
        for (int kc = 0; kc < 4; kc++) breg[kc] = Wg8[(kc * 8 + wv) * 64 + lane];

        float s[16];
        #pragma unroll
        for (int k = 0; k < 16; k++) s[k] = 0.f;
        int o0 = ooff[r * 64 + dl] - rbase;
        int o1 = ooff[r * 64 + dl + 1] - rbase;
        int nc = (cnt + 63) >> 6;

        for (int c = 0; c < nc; c++) {
            int cb0 = c * 64, m = min(64, cnt - cb0);
            if (c > 0) __syncthreads();          // prev reduce done, Raw reusable
            if (le < m) {
                int node = epack[rbase + cb0 + le];
                const short8* hp = (const short8*)(h1b + (size_t)node * D) + lp * 2;
                Raw8[le * 17 + lp * 2]     = hp[0];
                Raw8[le * 17 + lp * 2 + 1] = hp[1];
            }
            __syncthreads();                     // Raw visible
            int lo = max(o0 - cb0, 0), hi = min(o1 - cb0, m);
            for (int p = lo; p < hi; p++) {
                short8 w0 = Raw8[p * 17 + 2 * cg];
                short8 w1 = Raw8[p * 17 + 2 * cg + 1];
                #pragma unroll
                for (int k = 0; k < 8; k++) {
                    s[k]     += bf2f((unsigned short)w0[k]);
                    s[8 + k] += bf2f((unsigned short)w1[k]);
                }
            }
        }
        short8 p0, p1;
        #pragma unroll
        for (int k = 0; k < 8; k++) {
            p0[k] = (short)f2bf(s[k]);
            p1[k] = (short)f2bf(s[8 + k]);
        }
        Sl8[dl * 16 + ((cg * 2)     ^ (dl & 15))] = p0;
        Sl8[dl * 16 + ((cg * 2 + 1) ^ (dl & 15))] = p1;
        __syncthreads();                         // Sl visible (all reduces done)
        #pragma unroll
        for (int rb = 0; rb < 4; rb++) {
            int arow = rb * 16 + row;
            #pragma unroll
            for (int kc = 0; kc < 4; kc++) {
                short8 a = Sl8[arow * 16 + ((kc * 4 + gg) ^ (arow & 15))];
                acc[rb] = __builtin_amdgcn_mfma_f32_16x16x32_bf16(a, breg[kc], acc[rb], 0, 0, 0);
            }
        }
    }

    __syncthreads();                             // last-rel Sl reads done
    // epilogue part 1: bias + relu -> bf16 Af[64][136] (aliases Raw region)
    unsigned short* Af = (unsigned short*)lds;
    #pragma unroll
    for (int rb = 0; rb < 4; rb++) {
        #pragma unroll
        for (int reg = 0; reg < 4; reg++) {
            int rr = rb * 16 + gg * 4 + reg;
            int col = wv * 16 + row;
            Af[rr * 136 + col] = f2bf(fmaxf(acc[rb][reg] + bias1[col], 0.f));
        }
    }
    __syncthreads();
    // epilogue part 2: out[64x64] = Af @ lin_w + lin_b via MFMA
    {
        int rb = wv & 3;
        int nt0 = (wv >> 2) * 2, nt1 = nt0 + 1;
        f32x4 ao0 = (f32x4){0.f, 0.f, 0.f, 0.f};
        f32x4 ao1 = (f32x4){0.f, 0.f, 0.f, 0.f};
        #pragma unroll
        for (int kc = 0; kc < 4; kc++) {
            short8 a = *(const short8*)(Af + (rb * 16 + row) * 136 + kc * 32 + gg * 8);
            short8 b0 = *((const short8*)linWb + (kc * 4 + nt0) * 64 + lane);
            short8 b1 = *((const short8*)linWb + (kc * 4 + nt1) * 64 + lane);
            ao0 = __builtin_amdgcn_mfma_f32_16x16x32_bf16(a, b0, ao0, 0, 0, 0);
            ao1 = __builtin_amdgcn_mfma_f32_16x16x32_bf16(a, b1, ao1, 0, 0, 0);
        }
        float lb0 = lin_b[nt0 * 16 + row];
        float lb1 = lin_b[nt1 * 16 + row];
        #pragma unroll
        for (int reg = 0; reg < 4; reg++) {
            int d = tile * 64 + rb * 16 + gg * 4 + reg;
            if (d < NN) {
                out[d * DO + nt0 * 16 + row] = ao0[reg] + lb0;
                out[d * DO + nt1 * 16 + row] = ao1[reg] + lb1;
            }
        }
    }
}

extern "C" void kernel_launch(void* const* d_in, const int* in_sizes, int n_in,
                              void* d_out, int out_size, void* d_ws, size_t ws_size,
                              hipStream_t stream) {
    const int*   src    = (const int*)d_in[0];
    const int*   dst    = (const int*)d_in[1];
    const int*   et     = (const int*)d_in[2];
    const float* basis0 = (const float*)d_in[4];
    const float* wcomp0 = (const float*)d_in[5];
    const float* bias0  = (const float*)d_in[6];
    const float* basis1 = (const float*)d_in[7];
    const float* wcomp1 = (const float*)d_in[8];
    const float* bias1  = (const float*)d_in[9];
    const float* lin_w  = (const float*)d_in[10];
    const float* lin_b  = (const float*)d_in[11];
    float* out = (float*)d_out;

    char* ws = (char*)d_ws;
    int*            cnt2    = (int*)           (ws + 0);
    int*            bsum    = (int*)           (ws + 4003840);
    int*            scancnt = (int*)           (ws + 4007752);
    int*            boff2   = (int*)           (ws + 4007808);
    int*            gcur2   = (int*)           (ws + 8011712);
    float*          W0      = (float*)         (ws + 12015616);
    unsigned short* W1b     = (unsigned short*)(ws + 12025856);
    unsigned short* h1b     = (unsigned short*)(ws + 12681216);
    unsigned short* epack   = (unsigned short*)(ws + 25481216);
    unsigned short* linWb   = (unsigned short*)(ws + 28681216);

    // zero cnt2 + bsum + scancnt
    hipMemsetAsync(ws, 0, 4007756, stream);

    k_wh<<<NT, 1024, 0, stream>>>(basis0, wcomp0, basis1, wcomp1, lin_w,
                                  dst, et, W0, W1b, linWb, cnt2);
    k_scan1<<<NSB, 1024, 0, stream>>>(cnt2, boff2, bsum, scancnt);
    k_mid<<<NSB, 1024, 0, stream>>>(boff2, bsum, gcur2, cnt2, W0, bias0, h1b);
    k_scatter<<<NT, 1024, 0, stream>>>(src, dst, et, gcur2, epack);
    k_mega<<<NT, 512, 0, stream>>>(epack, boff2, h1b, W1b, linWb,
                                   bias1, lin_b, out);
}

// Round 15
// 212.026 us; speedup vs baseline: 1.0215x; 1.0215x over previous
//
#include <hip/hip_runtime.h>
#include <hip/hip_bf16.h>

#define NN 50000      // nodes
#define NE 800000     // edges
#define NR 20         // relations
#define NB 8          // bases
#define D  128        // hidden dim
#define DO 64         // output dim
#define NT 782        // ceil(NN/64) dst tiles
#define NBKT (NT*1280) // (tile, rel, dl) buckets = 1,000,960
#define NSB 978       // ceil(NBKT/1024)

typedef __attribute__((ext_vector_type(8))) short short8;
typedef __attribute__((ext_vector_type(4))) float f32x4;

__device__ inline unsigned short f2bf(float f) {
    __hip_bfloat16 h = __float2bfloat16(f);
    return *reinterpret_cast<unsigned short*>(&h);
}
__device__ inline float bf2f(unsigned short u) {
    unsigned x = ((unsigned)u) << 16;
    float f;
    __builtin_memcpy(&f, &x, 4);
    return f;
}

// ---------------------------------------------------------------------------
// ws layout (bytes):
//   [0        ..  4,003,840) cnt2    NBKT int  -- zeroed each call
//   [4,003,840..  4,007,752) bsum    NSB int   -- zeroed (rewritten by scan1)
//   [4,007,752..  4,007,756) scancnt int       -- zeroed each call
//   [4,007,808..  8,011,652) boff2   NBKT+1 int
//   [8,011,712.. 12,015,552) gcur2   NBKT int
//   [12,015,616..12,025,856) W0      NR*D f32
//   [12,025,856..12,681,216) W1b     NR*16384 bf16 (B-fragment order)
//   [12,681,216..25,481,216) h1b     NN*D bf16
//   [25,481,216..27,081,216) epack   NE ushort (src ids, sorted by (tile,r,dl))
//   [28,681,216..28,697,600) linWb   lin_w in B-fragment order, bf16
// ---------------------------------------------------------------------------

// Fused weights+hist, straggler-free: blocks 0..39 build weights ONLY;
// blocks 40..821 do the (tile,rel,dl) histogram ONLY (run concurrently).
__global__ __launch_bounds__(1024) void k_wh(
        const float* __restrict__ basis0, const float* __restrict__ wcomp0,
        const float* __restrict__ basis1, const float* __restrict__ wcomp1,
        const float* __restrict__ lin_w,
        const int* __restrict__ dst, const int* __restrict__ et,
        float* __restrict__ W0, unsigned short* __restrict__ W1b,
        unsigned short* __restrict__ linWb, int* __restrict__ cnt2) {
    int b = blockIdx.x;
    if (b < 40) {
        int idx = b * 1024 + threadIdx.x;       // 0..40959
        if (idx < NR * D) {
            int r = idx / D, o = idx % D;
            float a = 0.f;
            #pragma unroll
            for (int bb = 0; bb < NB; bb++) a += wcomp0[r * NB + bb] * basis0[bb * D + o];
            W0[idx] = a;
        }
        if (idx < 16 * 64) {
            int lane = idx & 63, fr = idx >> 6;
            int kc = fr >> 2, nt = fr & 3;
            int i0 = kc * 32 + (lane >> 4) * 8;
            int o = nt * 16 + (lane & 15);
            short8 v;
            #pragma unroll
            for (int e = 0; e < 8; e++) v[e] = (short)f2bf(lin_w[(i0 + e) * DO + o]);
            *((short8*)linWb + idx) = v;
        }
        {
            int lane = idx & 63;
            int cb   = (idx >> 6) & 7;
            int kc   = (idx >> 9) & 3;
            int rel  = idx >> 11;
            float wc[NB];
            #pragma unroll
            for (int bb = 0; bb < NB; bb++) wc[bb] = wcomp1[rel * NB + bb];
            int o  = cb * 16 + (lane & 15);
            int i0 = kc * 32 + (lane >> 4) * 8;
            short8 v;
            #pragma unroll
            for (int e = 0; e < 8; e++) {
                int i = i0 + e;
                float a = 0.f;
                #pragma unroll
                for (int bb = 0; bb < NB; bb++) a += wc[bb] * basis1[(bb * D + i) * D + o];
                v[e] = (short)f2bf(a);
            }
            *((short8*)W1b + idx) = v;
        }
    } else {
        int i = (b - 40) * 1024 + threadIdx.x;
        if (i < NE) {
            int d = dst[i];
            int key = (d >> 6) * 1280 + et[i] * 64 + (d & 63);
            atomicAdd(&cnt2[key], 1);
        }
    }
}

// Scan phase 1 + fused phase 2 (last-finishing block scans bsum in place).
__global__ __launch_bounds__(1024) void k_scan1(const int* __restrict__ cnt2,
                                                int* __restrict__ boff2,
                                                int* __restrict__ bsum,
                                                int* __restrict__ scancnt) {
    __shared__ int ws[16];
    __shared__ int lastf;
    int t = threadIdx.x, lane = t & 63, wv = t >> 6;
    int i = blockIdx.x * 1024 + t;
    int v = (i < NBKT) ? cnt2[i] : 0;
    int inc = v;
    for (int dd = 1; dd < 64; dd <<= 1) {
        int u = __shfl_up(inc, dd);
        if (lane >= dd) inc += u;
    }
    if (lane == 63) ws[wv] = inc;
    __syncthreads();
    if (t == 0) { int a = 0; for (int j = 0; j < 16; j++) { int x = ws[j]; ws[j] = a; a += x; } }
    __syncthreads();
    int ex = ws[wv] + inc - v;
    if (i < NBKT) boff2[i] = ex;
    if (t == 1023) {
        bsum[blockIdx.x] = ex + v;
        __threadfence();
        int done = atomicAdd(scancnt, 1);
        lastf = (done == (int)gridDim.x - 1);
    }
    __syncthreads();
    if (!lastf) return;
    // fused scan2: this block scans bsum (device-scope RMW reads)
    int v2 = (t < NSB) ? atomicAdd(&bsum[t], 0) : 0;
    int inc2 = v2;
    for (int dd = 1; dd < 64; dd <<= 1) {
        int u = __shfl_up(inc2, dd);
        if (lane >= dd) inc2 += u;
    }
    __syncthreads();
    if (lane == 63) ws[wv] = inc2;
    __syncthreads();
    if (t == 0) { int a = 0; for (int j = 0; j < 16; j++) { int x = ws[j]; ws[j] = a; a += x; } }
    __syncthreads();
    if (t < NSB) bsum[t] = ws[wv] + inc2 - v2;
}

// Fused: scan phase 3 (all 978 blocks) + h1 compute (blocks < NT).
__global__ __launch_bounds__(1024) void k_mid(
        int* __restrict__ boff2, const int* __restrict__ bsum,
        int* __restrict__ gcur2, const int* __restrict__ cnt2,
        const float* __restrict__ W0, const float* __restrict__ bias0,
        unsigned short* __restrict__ h1b) {
    __shared__ float cs[NR * 64];
    __shared__ float w0s[NR * D];
    int t = threadIdx.x, b = blockIdx.x;
    int i = b * 1024 + t;
    if (i < NBKT) {
        int f = boff2[i] + bsum[i >> 10];
        boff2[i] = f;
        gcur2[i] = f;
    }
    if (i == 0) boff2[NBKT] = NE;
    if (b < NT) {
        for (int j = t; j < NR * 64; j += 1024) cs[j] = (float)cnt2[b * 1280 + j];
        for (int j = t; j < NR * D; j += 1024) w0s[j] = W0[j];
        __syncthreads();
        int nl = t >> 4, cg = t & 15;          // node-local, col-group of 8
        int n = b * 64 + nl;
        if (n < NN) {
            float a[8];
            #pragma unroll
            for (int j = 0; j < 8; j++) a[j] = bias0[cg * 8 + j];
            for (int r = 0; r < NR; r++) {
                float c = cs[r * 64 + nl];
                #pragma unroll
                for (int j = 0; j < 8; j++) a[j] += c * w0s[r * D + cg * 8 + j];
            }
            short8 o;
            #pragma unroll
            for (int j = 0; j < 8; j++) o[j] = (short)f2bf(fmaxf(a[j], 0.f));
            *((short8*)(h1b + n * D + cg * 8)) = o;
        }
    }
}

// Counting-sort scatter: epack[pos] = src (ushort), grouped by (tile,rel,dl).
__global__ __launch_bounds__(1024) void k_scatter(
        const int* __restrict__ src, const int* __restrict__ dst,
        const int* __restrict__ et, int* __restrict__ gcur2,
        unsigned short* __restrict__ epack) {
    int i = blockIdx.x * 1024 + threadIdx.x;
    if (i < NE) {
        int d = dst[i];
        int key = (d >> 6) * 1280 + et[i] * 64 + (d & 63);
        int pos = atomicAdd(&gcur2[key], 1);
        epack[pos] = (unsigned short)src[i];
    }
}

// Mega v12 = r13-proven body + epk/ooffs in LDS (cuts the dependent epack L2
// read out of every per-rel chain). 512 thr / 64-dst tile; wave wv owns output
// cols wv*16..+15 for all 64 rows. Per rel: 4 B-frag register loads (reused
// 4x) at rel-top; stage 64 rows -> Raw (node ids from LDS epk); reduce own
// bucket; publish swizzled Sl; 16 MFMA. 2 barriers/rel.
// LDS = 17408 (Raw) + 16384 (Sl) + 2564 (ooffs u16) + 4096 (epk) ~= 40.5 KB.
__global__ __launch_bounds__(512, 2) void k_mega(
        const unsigned short* __restrict__ epack, const int* __restrict__ boff2,
        const unsigned short* __restrict__ h1b,
        const unsigned short* __restrict__ W1b,
        const unsigned short* __restrict__ linWb,
        const float* __restrict__ bias1, const float* __restrict__ lin_b,
        float* __restrict__ out) {
    __shared__ __align__(16) char lds[17408 + 16384];  // Raw 64x17s8 | Sl 64x16s8
    __shared__ unsigned short ooffs[1282];             // tile-relative offsets
    __shared__ unsigned short epk[2048];               // tile's src ids

    short8* Raw8 = (short8*)lds;
    short8* Sl8  = (short8*)(lds + 17408);

    int t = threadIdx.x, tile = blockIdx.x;
    int wv = t >> 6, lane = t & 63;
    int le = t >> 3, lp = t & 7;             // stage role: edge row, 16B pair
    int dl = t >> 3, cg = t & 7;             // reduce role: dst-local, col-group
    int row = lane & 15, gg = lane >> 4;     // mfma role

    int kbase = tile * 1280;
    int tb = boff2[kbase];
    for (int i = t; i < 1281; i += 512)
        ooffs[i] = (unsigned short)(boff2[kbase + i] - tb);
    __syncthreads();
    int nE = min((int)ooffs[1280], 2048);
    for (int i = t; i < nE; i += 512) epk[i] = epack[tb + i];
    __syncthreads();

    f32x4 acc[4];
    #pragma unroll
    for (int j = 0; j < 4; j++) acc[j] = (f32x4){0.f, 0.f, 0.f, 0.f};

    for (int r = 0; r < NR; r++) {
        int rbase = ooffs[r * 64];
        int cnt = ooffs[r * 64 + 64] - rbase;    // block-uniform
        if (cnt == 0) continue;

        const short8* Wg8 = (const short8*)W1b + r * 2048;
        short8 breg[4];
        #pragma unroll
        for (int kc = 0; kc < 4; kc++) breg[kc] = Wg8[(kc * 8 + wv) * 64 + lane];

        float s[16];
        #pragma unroll
        for (int k = 0; k < 16; k++) s[k] = 0.f;
        int o0 = ooffs[r * 64 + dl] - rbase;
        int o1 = ooffs[r * 64 + dl + 1] - rbase;
        int nc = (cnt + 63) >> 6;

        for (int c = 0; c < nc; c++) {
            int cb0 = c * 64, m = min(64, cnt - cb0);
            if (c > 0) __syncthreads();          // prev reduce done, Raw reusable
            if (le < m) {
                int node = epk[rbase + cb0 + le];
                const short8* hp = (const short8*)(h1b + (size_t)node * D) + lp * 2;
                Raw8[le * 17 + lp * 2]     = hp[0];
                Raw8[le * 17 + lp * 2 + 1] = hp[1];
            }
            __syncthreads();                     // Raw visible
            int lo = max(o0 - cb0, 0), hi = min(o1 - cb0, m);
            for (int p = lo; p < hi; p++) {
                short8 w0 = Raw8[p * 17 + 2 * cg];
                short8 w1 = Raw8[p * 17 + 2 * cg + 1];
                #pragma unroll
                for (int k = 0; k < 8; k++) {
                    s[k]     += bf2f((unsigned short)w0[k]);
                    s[8 + k] += bf2f((unsigned short)w1[k]);
                }
            }
        }
        short8 p0, p1;
        #pragma unroll
        for (int k = 0; k < 8; k++) {
            p0[k] = (short)f2bf(s[k]);
            p1[k] = (short)f2bf(s[8 + k]);
        }
        Sl8[dl * 16 + ((cg * 2)     ^ (dl & 15))] = p0;
        Sl8[dl * 16 + ((cg * 2 + 1) ^ (dl & 15))] = p1;
        __syncthreads();                         // Sl visible (all reduces done)
        #pragma unroll
        for (int rb = 0; rb < 4; rb++) {
            int arow = rb * 16 + row;
            #pragma unroll
            for (int kc = 0; kc < 4; kc++) {
                short8 a = Sl8[arow * 16 + ((kc * 4 + gg) ^ (arow & 15))];
                acc[rb] = __builtin_amdgcn_mfma_f32_16x16x32_bf16(a, breg[kc], acc[rb], 0, 0, 0);
            }
        }
    }

    __syncthreads();                             // last-rel Sl reads done
    // epilogue part 1: bias + relu -> bf16 Af[64][136] (aliases Raw region)
    unsigned short* Af = (unsigned short*)lds;
    #pragma unroll
    for (int rb = 0; rb < 4; rb++) {
        #pragma unroll
        for (int reg = 0; reg < 4; reg++) {
            int rr = rb * 16 + gg * 4 + reg;
            int col = wv * 16 + row;
            Af[rr * 136 + col] = f2bf(fmaxf(acc[rb][reg] + bias1[col], 0.f));
        }
    }
    __syncthreads();
    // epilogue part 2: out[64x64] = Af @ lin_w + lin_b via MFMA
    {
        int rb = wv & 3;
        int nt0 = (wv >> 2) * 2, nt1 = nt0 + 1;
        f32x4 ao0 = (f32x4){0.f, 0.f, 0.f, 0.f};
        f32x4 ao1 = (f32x4){0.f, 0.f, 0.f, 0.f};
        #pragma unroll
        for (int kc = 0; kc < 4; kc++) {
            short8 a = *(const short8*)(Af + (rb * 16 + row) * 136 + kc * 32 + gg * 8);
            short8 b0 = *((const short8*)linWb + (kc * 4 + nt0) * 64 + lane);
            short8 b1 = *((const short8*)linWb + (kc * 4 + nt1) * 64 + lane);
            ao0 = __builtin_amdgcn_mfma_f32_16x16x32_bf16(a, b0, ao0, 0, 0, 0);
            ao1 = __builtin_amdgcn_mfma_f32_16x16x32_bf16(a, b1, ao1, 0, 0, 0);
        }
        float lb0 = lin_b[nt0 * 16 + row];
        float lb1 = lin_b[nt1 * 16 + row];
        #pragma unroll
        for (int reg = 0; reg < 4; reg++) {
            int d = tile * 64 + rb * 16 + gg * 4 + reg;
            if (d < NN) {
                out[d * DO + nt0 * 16 + row] = ao0[reg] + lb0;
                out[d * DO + nt1 * 16 + row] = ao1[reg] + lb1;
            }
        }
    }
}

extern "C" void kernel_launch(void* const* d_in, const int* in_sizes, int n_in,
                              void* d_out, int out_size, void* d_ws, size_t ws_size,
                              hipStream_t stream) {
    const int*   src    = (const int*)d_in[0];
    const int*   dst    = (const int*)d_in[1];
    const int*   et     = (const int*)d_in[2];
    const float* basis0 = (const float*)d_in[4];
    const float* wcomp0 = (const float*)d_in[5];
    const float* bias0  = (const float*)d_in[6];
    const float* basis1 = (const float*)d_in[7];
    const float* wcomp1 = (const float*)d_in[8];
    const float* bias1  = (const float*)d_in[9];
    const float* lin_w  = (const float*)d_in[10];
    const float* lin_b  = (const float*)d_in[11];
    float* out = (float*)d_out;

    char* ws = (char*)d_ws;
    int*            cnt2    = (int*)           (ws + 0);
    int*            bsum    = (int*)           (ws + 4003840);
    int*            scancnt = (int*)           (ws + 4007752);
    int*            boff2   = (int*)           (ws + 4007808);
    int*            gcur2   = (int*)           (ws + 8011712);
    float*          W0      = (float*)         (ws + 12015616);
    unsigned short* W1b     = (unsigned short*)(ws + 12025856);
    unsigned short* h1b     = (unsigned short*)(ws + 12681216);
    unsigned short* epack   = (unsigned short*)(ws + 25481216);
    unsigned short* linWb   = (unsigned short*)(ws + 28681216);

    // zero cnt2 + bsum + scancnt
    hipMemsetAsync(ws, 0, 4007756, stream);

    k_wh<<<NT + 40, 1024, 0, stream>>>(basis0, wcomp0, basis1, wcomp1, lin_w,
                                       dst, et, W0, W1b, linWb, cnt2);
    k_scan1<<<NSB, 1024, 0, stream>>>(cnt2, boff2, bsum, scancnt);
    k_mid<<<NSB, 1024, 0, stream>>>(boff2, bsum, gcur2, cnt2, W0, bias0, h1b);
    k_scatter<<<NT, 1024, 0, stream>>>(src, dst, et, gcur2, epack);
    k_mega<<<NT, 512, 0, stream>>>(epack, boff2, h1b, W1b, linWb,
                                   bias1, lin_b, out);
}

// Round 16
// 202.863 us; speedup vs baseline: 1.0676x; 1.0452x over previous
//
#include <hip/hip_runtime.h>
#include <hip/hip_bf16.h>

#define NN 50000      // nodes
#define NE 800000     // edges
#define NR 20         // relations
#define NB 8          // bases
#define D  128        // hidden dim
#define DO 64         // output dim
#define NT 782        // ceil(NN/64) dst tiles
#define NBKT (NT*1280) // (tile, rel, dl) buckets = 1,000,960
#define NSB 978       // ceil(NBKT/1024)

typedef __attribute__((ext_vector_type(8))) short short8;
typedef __attribute__((ext_vector_type(4))) float f32x4;

__device__ inline unsigned short f2bf(float f) {
    __hip_bfloat16 h = __float2bfloat16(f);
    return *reinterpret_cast<unsigned short*>(&h);
}
__device__ inline float bf2f(unsigned short u) {
    unsigned x = ((unsigned)u) << 16;
    float f;
    __builtin_memcpy(&f, &x, 4);
    return f;
}

// ---------------------------------------------------------------------------
// ws layout (bytes):
//   [0        ..  4,003,840) cnt2    NBKT int  -- zeroed each call
//   [4,003,840..  4,007,752) bsum    NSB int   -- rewritten by scan1
//   [4,007,808..  8,011,652) boff2   NBKT+1 int
//   [8,011,712.. 12,015,552) gcur2   NBKT int
//   [12,015,616..12,025,856) W0      NR*D f32
//   [12,025,856..12,681,216) W1b     NR*16384 bf16 (B-fragment order)
//   [12,681,216..25,481,216) h1b     NN*D bf16
//   [25,481,216..27,081,216) epack   NE ushort (src ids, sorted by (tile,r,dl))
//   [28,681,216..28,697,600) linWb   lin_w in B-fragment order, bf16
// ---------------------------------------------------------------------------

__global__ __launch_bounds__(256) void k_weights(
        const float* __restrict__ basis0, const float* __restrict__ wcomp0,
        const float* __restrict__ basis1, const float* __restrict__ wcomp1,
        const float* __restrict__ lin_w,
        float* __restrict__ W0, unsigned short* __restrict__ W1b,
        unsigned short* __restrict__ linWb) {
    int idx = blockIdx.x * 256 + threadIdx.x;   // 0..40959
    if (idx < NR * D) {
        int r = idx / D, o = idx % D;
        float a = 0.f;
        #pragma unroll
        for (int b = 0; b < NB; b++) a += wcomp0[r * NB + b] * basis0[b * D + o];
        W0[idx] = a;
    }
    if (idx < 16 * 64) {
        int lane = idx & 63, fr = idx >> 6;
        int kc = fr >> 2, nt = fr & 3;
        int i0 = kc * 32 + (lane >> 4) * 8;
        int o = nt * 16 + (lane & 15);
        short8 v;
        #pragma unroll
        for (int e = 0; e < 8; e++) v[e] = (short)f2bf(lin_w[(i0 + e) * DO + o]);
        *((short8*)linWb + idx) = v;
    }
    if (idx < NR * 4 * 8 * 64) {
        int lane = idx & 63;
        int cb   = (idx >> 6) & 7;
        int kc   = (idx >> 9) & 3;
        int rel  = idx >> 11;
        float wc[NB];
        #pragma unroll
        for (int b = 0; b < NB; b++) wc[b] = wcomp1[rel * NB + b];
        int o  = cb * 16 + (lane & 15);
        int i0 = kc * 32 + (lane >> 4) * 8;
        short8 v;
        #pragma unroll
        for (int e = 0; e < 8; e++) {
            int i = i0 + e;
            float a = 0.f;
            #pragma unroll
            for (int b = 0; b < NB; b++) a += wc[b] * basis1[(b * D + i) * D + o];
            v[e] = (short)f2bf(a);
        }
        *((short8*)W1b + idx) = v;
    }
}

__global__ __launch_bounds__(1024) void k_hist(
        const int* __restrict__ dst, const int* __restrict__ et,
        int* __restrict__ cnt2) {
    int i = blockIdx.x * 1024 + threadIdx.x;
    if (i < NE) {
        int d = dst[i];
        int key = (d >> 6) * 1280 + et[i] * 64 + (d & 63);
        atomicAdd(&cnt2[key], 1);
    }
}

__global__ __launch_bounds__(1024) void k_scan1(const int* __restrict__ cnt2,
                                                int* __restrict__ boff2,
                                                int* __restrict__ bsum) {
    __shared__ int ws[16];
    int t = threadIdx.x, lane = t & 63, wv = t >> 6;
    int i = blockIdx.x * 1024 + t;
    int v = (i < NBKT) ? cnt2[i] : 0;
    int inc = v;
    for (int dd = 1; dd < 64; dd <<= 1) {
        int u = __shfl_up(inc, dd);
        if (lane >= dd) inc += u;
    }
    if (lane == 63) ws[wv] = inc;
    __syncthreads();
    if (t == 0) { int a = 0; for (int j = 0; j < 16; j++) { int x = ws[j]; ws[j] = a; a += x; } }
    __syncthreads();
    int ex = ws[wv] + inc - v;
    if (i < NBKT) boff2[i] = ex;
    if (t == 1023) bsum[blockIdx.x] = ex + v;
}

__global__ __launch_bounds__(1024) void k_scan2(int* __restrict__ bsum) {
    __shared__ int ws[16];
    int t = threadIdx.x, lane = t & 63, wv = t >> 6;
    int v = (t < NSB) ? bsum[t] : 0;
    int inc = v;
    for (int dd = 1; dd < 64; dd <<= 1) {
        int u = __shfl_up(inc, dd);
        if (lane >= dd) inc += u;
    }
    if (lane == 63) ws[wv] = inc;
    __syncthreads();
    if (t == 0) { int a = 0; for (int j = 0; j < 16; j++) { int x = ws[j]; ws[j] = a; a += x; } }
    __syncthreads();
    if (t < NSB) bsum[t] = ws[wv] + inc - v;
}

__global__ __launch_bounds__(1024) void k_scan3(int* __restrict__ boff2,
                                                const int* __restrict__ bsum,
                                                int* __restrict__ gcur2) {
    int i = blockIdx.x * 1024 + threadIdx.x;
    if (i < NBKT) {
        int f = boff2[i] + bsum[i >> 10];
        boff2[i] = f;
        gcur2[i] = f;
    }
    if (i == 0) boff2[NBKT] = NE;
}

__global__ __launch_bounds__(512) void k_h1(const int* __restrict__ cnt2,
                                            const float* __restrict__ W0,
                                            const float* __restrict__ bias0,
                                            unsigned short* __restrict__ h1b) {
    __shared__ float cs[NR * 64];
    __shared__ float w0s[NR * D];
    int t = threadIdx.x, tile = blockIdx.x;
    for (int i = t; i < NR * 64; i += 512) cs[i] = (float)cnt2[tile * 1280 + i];
    for (int i = t; i < NR * D; i += 512) w0s[i] = W0[i];
    __syncthreads();
    int nl = t >> 3, cg = t & 7;
    int n = tile * 64 + nl;
    if (n < NN) {
        float a[16];
        #pragma unroll
        for (int j = 0; j < 16; j++) a[j] = bias0[cg * 16 + j];
        for (int r = 0; r < NR; r++) {
            float c = cs[r * 64 + nl];
            #pragma unroll
            for (int j = 0; j < 16; j++) a[j] += c * w0s[r * D + cg * 16 + j];
        }
        short8 o0, o1;
        #pragma unroll
        for (int j = 0; j < 8; j++) {
            o0[j] = (short)f2bf(fmaxf(a[j], 0.f));
            o1[j] = (short)f2bf(fmaxf(a[8 + j], 0.f));
        }
        *((short8*)(h1b + n * D + cg * 16))     = o0;
        *((short8*)(h1b + n * D + cg * 16 + 8)) = o1;
    }
}

__global__ __launch_bounds__(1024) void k_scatter(
        const int* __restrict__ src, const int* __restrict__ dst,
        const int* __restrict__ et, int* __restrict__ gcur2,
        unsigned short* __restrict__ epack) {
    int i = blockIdx.x * 1024 + threadIdx.x;
    if (i < NE) {
        int d = dst[i];
        int key = (d >> 6) * 1280 + et[i] * 64 + (d & 63);
        int pos = atomicAdd(&gcur2[key], 1);
        epack[pos] = (unsigned short)src[i];
    }
}

// Mega v13: software-pipelined chunk stream.
//  Flat (rel, chunk) stream; per iteration:
//   [c==0] deferred MFMA of PREVIOUS rel (reads Sl + breg; overlaps the
//          in-flight gather), then B-load for this rel into breg, zero s;
//   ds_write in-flight chunk regs -> Raw;  barrier1 (Raw visible);
//   issue NEXT chunk's h1b gather -> regs (hidden under reduce+MFMA+barriers);
//   reduce own bucket rows from Raw;  [last chunk of rel] publish swizzled Sl;
//   barrier2 (Raw reusable / Sl publish complete).
//  Final deferred MFMA after the loop. Epilogue unchanged (bf16 MFMA linear).
__global__ __launch_bounds__(512, 2) void k_mega(
        const unsigned short* __restrict__ epack, const int* __restrict__ boff2,
        const unsigned short* __restrict__ h1b,
        const unsigned short* __restrict__ W1b,
        const unsigned short* __restrict__ linWb,
        const float* __restrict__ bias1, const float* __restrict__ lin_b,
        float* __restrict__ out) {
    __shared__ __align__(16) char lds[17408 + 16384];  // Raw 64x17s8 | Sl 64x16s8
    __shared__ unsigned short ooffs[1282];             // tile-relative offsets
    __shared__ unsigned short epk[2048];               // tile's src ids
    __shared__ unsigned short ct[64];                  // chunk table (r<<3)|c
    __shared__ int nchS;

    short8* Raw8 = (short8*)lds;
    short8* Sl8  = (short8*)(lds + 17408);

    int t = threadIdx.x, tile = blockIdx.x;
    int wv = t >> 6, lane = t & 63;
    int le = t >> 3, lp = t & 7;             // stage role: edge row, 16B pair
    int dl = t >> 3, cg = t & 7;             // reduce role
    int row = lane & 15, gg = lane >> 4;     // mfma role

    int kbase = tile * 1280;
    int tb = boff2[kbase];
    for (int i = t; i < 1281; i += 512)
        ooffs[i] = (unsigned short)(boff2[kbase + i] - tb);
    __syncthreads();
    int nE = min((int)ooffs[1280], 2048);
    for (int i = t; i < nE; i += 512) epk[i] = epack[tb + i];
    if (t == 0) {
        int j = 0;
        for (int r = 0; r < NR; r++) {
            int cnt = (int)ooffs[r * 64 + 64] - (int)ooffs[r * 64];
            int nc = (cnt + 63) >> 6;          // 0 for empty rels
            for (int c = 0; c < nc; c++) ct[j++] = (unsigned short)((r << 3) | c);
        }
        nchS = j;
    }
    __syncthreads();
    int nch = nchS;

    f32x4 acc[4];
    #pragma unroll
    for (int j = 0; j < 4; j++) acc[j] = (f32x4){0.f, 0.f, 0.f, 0.f};
    float s[16];
    short8 v0 = {0,0,0,0,0,0,0,0}, v1 = v0;
    short8 breg[4];
    int pend = -1;

    // issue chunk 0 gather
    if (nch > 0) {
        int e = ct[0]; int r = e >> 3;
        int rbase = ooffs[r * 64];
        int cnt = (int)ooffs[r * 64 + 64] - rbase;
        int m = min(64, cnt);
        if (le < m) {
            int node = epk[rbase + le];
            const short8* hp = (const short8*)(h1b + (size_t)node * D) + lp * 2;
            v0 = hp[0]; v1 = hp[1];
        }
    }

    for (int k = 0; k < nch; k++) {
        int e = ct[k]; int r = e >> 3, c = e & 7;
        int rbase = ooffs[r * 64];
        int cnt = (int)ooffs[r * 64 + 64] - rbase;
        int cb0 = c << 6;
        int m = min(64, cnt - cb0);
        bool lastofrel = (cb0 + 64 >= cnt);

        if (c == 0) {
            if (pend >= 0) {                 // deferred MFMA of previous rel
                __builtin_amdgcn_s_setprio(1);
                #pragma unroll
                for (int rb = 0; rb < 4; rb++) {
                    int arow = rb * 16 + row;
                    #pragma unroll
                    for (int kc = 0; kc < 4; kc++) {
                        short8 a = Sl8[arow * 16 + ((kc * 4 + gg) ^ (arow & 15))];
                        acc[rb] = __builtin_amdgcn_mfma_f32_16x16x32_bf16(a, breg[kc], acc[rb], 0, 0, 0);
                    }
                }
                __builtin_amdgcn_s_setprio(0);
            }
            const short8* Wg8 = (const short8*)W1b + r * 2048;
            #pragma unroll
            for (int kc = 0; kc < 4; kc++) breg[kc] = Wg8[(kc * 8 + wv) * 64 + lane];
            #pragma unroll
            for (int kk = 0; kk < 16; kk++) s[kk] = 0.f;
        }
        // write in-flight chunk to Raw
        if (le < m) {
            Raw8[le * 17 + lp * 2]     = v0;
            Raw8[le * 17 + lp * 2 + 1] = v1;
        }
        __syncthreads();                     // barrier1: Raw visible
        // issue next chunk's gather (hidden under reduce + next MFMA)
        if (k + 1 < nch) {
            int e2 = ct[k + 1]; int r2 = e2 >> 3, c2 = e2 & 7;
            int rb2 = ooffs[r2 * 64];
            int c2v = (int)ooffs[r2 * 64 + 64] - rb2;
            int m2 = min(64, c2v - (c2 << 6));
            if (le < m2) {
                int node = epk[rb2 + (c2 << 6) + le];
                const short8* hp = (const short8*)(h1b + (size_t)node * D) + lp * 2;
                v0 = hp[0]; v1 = hp[1];
            }
        }
        // reduce own bucket's rows of this chunk
        {
            int o0 = (int)ooffs[r * 64 + dl] - rbase;
            int o1 = (int)ooffs[r * 64 + dl + 1] - rbase;
            int lo = max(o0 - cb0, 0), hi = min(o1 - cb0, m);
            for (int p = lo; p < hi; p++) {
                short8 w0 = Raw8[p * 17 + 2 * cg];
                short8 w1 = Raw8[p * 17 + 2 * cg + 1];
                #pragma unroll
                for (int kk = 0; kk < 8; kk++) {
                    s[kk]     += bf2f((unsigned short)w0[kk]);
                    s[8 + kk] += bf2f((unsigned short)w1[kk]);
                }
            }
        }
        if (lastofrel) {
            short8 p0, p1;
            #pragma unroll
            for (int kk = 0; kk < 8; kk++) {
                p0[kk] = (short)f2bf(s[kk]);
                p1[kk] = (short)f2bf(s[8 + kk]);
            }
            Sl8[dl * 16 + ((cg * 2)     ^ (dl & 15))] = p0;
            Sl8[dl * 16 + ((cg * 2 + 1) ^ (dl & 15))] = p1;
            pend = r;
        }
        __syncthreads();                     // barrier2: Raw reusable, Sl done
    }
    if (pend >= 0) {                         // final deferred MFMA
        #pragma unroll
        for (int rb = 0; rb < 4; rb++) {
            int arow = rb * 16 + row;
            #pragma unroll
            for (int kc = 0; kc < 4; kc++) {
                short8 a = Sl8[arow * 16 + ((kc * 4 + gg) ^ (arow & 15))];
                acc[rb] = __builtin_amdgcn_mfma_f32_16x16x32_bf16(a, breg[kc], acc[rb], 0, 0, 0);
            }
        }
    }

    __syncthreads();                         // all Sl reads done
    // epilogue part 1: bias + relu -> bf16 Af[64][136] (aliases Raw region)
    unsigned short* Af = (unsigned short*)lds;
    #pragma unroll
    for (int rb = 0; rb < 4; rb++) {
        #pragma unroll
        for (int reg = 0; reg < 4; reg++) {
            int rr = rb * 16 + gg * 4 + reg;
            int col = wv * 16 + row;
            Af[rr * 136 + col] = f2bf(fmaxf(acc[rb][reg] + bias1[col], 0.f));
        }
    }
    __syncthreads();
    // epilogue part 2: out[64x64] = Af @ lin_w + lin_b via MFMA
    {
        int rb = wv & 3;
        int nt0 = (wv >> 2) * 2, nt1 = nt0 + 1;
        f32x4 ao0 = (f32x4){0.f, 0.f, 0.f, 0.f};
        f32x4 ao1 = (f32x4){0.f, 0.f, 0.f, 0.f};
        #pragma unroll
        for (int kc = 0; kc < 4; kc++) {
            short8 a = *(const short8*)(Af + (rb * 16 + row) * 136 + kc * 32 + gg * 8);
            short8 b0 = *((const short8*)linWb + (kc * 4 + nt0) * 64 + lane);
            short8 b1 = *((const short8*)linWb + (kc * 4 + nt1) * 64 + lane);
            ao0 = __builtin_amdgcn_mfma_f32_16x16x32_bf16(a, b0, ao0, 0, 0, 0);
            ao1 = __builtin_amdgcn_mfma_f32_16x16x32_bf16(a, b1, ao1, 0, 0, 0);
        }
        float lb0 = lin_b[nt0 * 16 + row];
        float lb1 = lin_b[nt1 * 16 + row];
        #pragma unroll
        for (int reg = 0; reg < 4; reg++) {
            int d = tile * 64 + rb * 16 + gg * 4 + reg;
            if (d < NN) {
                out[d * DO + nt0 * 16 + row] = ao0[reg] + lb0;
                out[d * DO + nt1 * 16 + row] = ao1[reg] + lb1;
            }
        }
    }
}

extern "C" void kernel_launch(void* const* d_in, const int* in_sizes, int n_in,
                              void* d_out, int out_size, void* d_ws, size_t ws_size,
                              hipStream_t stream) {
    const int*   src    = (const int*)d_in[0];
    const int*   dst    = (const int*)d_in[1];
    const int*   et     = (const int*)d_in[2];
    const float* basis0 = (const float*)d_in[4];
    const float* wcomp0 = (const float*)d_in[5];
    const float* bias0  = (const float*)d_in[6];
    const float* basis1 = (const float*)d_in[7];
    const float* wcomp1 = (const float*)d_in[8];
    const float* bias1  = (const float*)d_in[9];
    const float* lin_w  = (const float*)d_in[10];
    const float* lin_b  = (const float*)d_in[11];
    float* out = (float*)d_out;

    char* ws = (char*)d_ws;
    int*            cnt2    = (int*)           (ws + 0);
    int*            bsum    = (int*)           (ws + 4003840);
    int*            boff2   = (int*)           (ws + 4007808);
    int*            gcur2   = (int*)           (ws + 8011712);
    float*          W0      = (float*)         (ws + 12015616);
    unsigned short* W1b     = (unsigned short*)(ws + 12025856);
    unsigned short* h1b     = (unsigned short*)(ws + 12681216);
    unsigned short* epack   = (unsigned short*)(ws + 25481216);
    unsigned short* linWb   = (unsigned short*)(ws + 28681216);

    hipMemsetAsync(ws, 0, 4003840, stream);   // zero cnt2

    k_weights<<<160, 256, 0, stream>>>(basis0, wcomp0, basis1, wcomp1, lin_w,
                                       W0, W1b, linWb);
    k_hist<<<782, 1024, 0, stream>>>(dst, et, cnt2);
    k_scan1<<<NSB, 1024, 0, stream>>>(cnt2, boff2, bsum);
    k_scan2<<<1, 1024, 0, stream>>>(bsum);
    k_scan3<<<NSB, 1024, 0, stream>>>(boff2, bsum, gcur2);
    k_h1<<<NT, 512, 0, stream>>>(cnt2, W0, bias0, h1b);
    k_scatter<<<NT, 1024, 0, stream>>>(src, dst, et, gcur2, epack);
    k_mega<<<NT, 512, 0, stream>>>(epack, boff2, h1b, W1b, linWb,
                                   bias1, lin_b, out);
}

// Round 17
// 190.044 us; speedup vs baseline: 1.1396x; 1.0675x over previous
//
#include <hip/hip_runtime.h>
#include <hip/hip_bf16.h>

#define NN 50000      // nodes
#define NE 800000     // edges
#define NR 20         // relations
#define NB 8          // bases
#define D  128        // hidden dim
#define DO 64         // output dim
#define NT 782        // ceil(NN/64) dst tiles
#define NBKT (NT*1280) // (tile, rel, dl) buckets = 1,000,960
#define NSB 978       // ceil(NBKT/1024)

typedef __attribute__((ext_vector_type(8))) short short8;
typedef __attribute__((ext_vector_type(4))) float f32x4;

__device__ inline unsigned short f2bf(float f) {
    __hip_bfloat16 h = __float2bfloat16(f);
    return *reinterpret_cast<unsigned short*>(&h);
}
__device__ inline float bf2f(unsigned short u) {
    unsigned x = ((unsigned)u) << 16;
    float f;
    __builtin_memcpy(&f, &x, 4);
    return f;
}

// ---------------------------------------------------------------------------
// ws layout (bytes):
//   [0        ..  4,003,840) cnt2    NBKT int  -- zeroed each call
//   [4,003,840..  4,007,752) bsum    NSB int   -- rewritten by scan1
//   [4,007,808..  8,011,652) boff2   NBKT+1 int
//   [8,011,712.. 12,015,552) gcur2   NBKT int
//   [12,015,616..12,025,856) W0      NR*D f32
//   [12,025,856..12,681,216) W1b     NR*16384 bf16 (B-fragment order)
//   [12,681,216..25,481,216) h1b     NN*D bf16
//   [25,481,216..27,081,216) epack   NE ushort (src ids, sorted by (tile,r,dl))
//   [28,681,216..28,697,600) linWb   lin_w in B-fragment order, bf16
// ---------------------------------------------------------------------------

// Fused hist+weights, role-split (no mixed-role straggler blocks):
//   blocks 0..781  : (tile,rel,dl) histogram only
//   blocks 782..821: weights build only (idx = (b-782)*1024 + t covers 40960)
__global__ __launch_bounds__(1024) void k_wh(
        const int* __restrict__ dst, const int* __restrict__ et,
        const float* __restrict__ basis0, const float* __restrict__ wcomp0,
        const float* __restrict__ basis1, const float* __restrict__ wcomp1,
        const float* __restrict__ lin_w,
        int* __restrict__ cnt2, float* __restrict__ W0,
        unsigned short* __restrict__ W1b, unsigned short* __restrict__ linWb) {
    int b = blockIdx.x;
    if (b < NT) {
        int i = b * 1024 + threadIdx.x;
        if (i < NE) {
            int d = dst[i];
            int key = (d >> 6) * 1280 + et[i] * 64 + (d & 63);
            atomicAdd(&cnt2[key], 1);
        }
        return;
    }
    int idx = (b - NT) * 1024 + threadIdx.x;    // 0..40959
    if (idx < NR * D) {
        int r = idx / D, o = idx % D;
        float a = 0.f;
        #pragma unroll
        for (int bb = 0; bb < NB; bb++) a += wcomp0[r * NB + bb] * basis0[bb * D + o];
        W0[idx] = a;
    }
    if (idx < 16 * 64) {
        int lane = idx & 63, fr = idx >> 6;
        int kc = fr >> 2, nt = fr & 3;
        int i0 = kc * 32 + (lane >> 4) * 8;
        int o = nt * 16 + (lane & 15);
        short8 v;
        #pragma unroll
        for (int e = 0; e < 8; e++) v[e] = (short)f2bf(lin_w[(i0 + e) * DO + o]);
        *((short8*)linWb + idx) = v;
    }
    if (idx < NR * 4 * 8 * 64) {
        int lane = idx & 63;
        int cb   = (idx >> 6) & 7;
        int kc   = (idx >> 9) & 3;
        int rel  = idx >> 11;
        float wc[NB];
        #pragma unroll
        for (int bb = 0; bb < NB; bb++) wc[bb] = wcomp1[rel * NB + bb];
        int o  = cb * 16 + (lane & 15);
        int i0 = kc * 32 + (lane >> 4) * 8;
        short8 v;
        #pragma unroll
        for (int e = 0; e < 8; e++) {
            int i = i0 + e;
            float a = 0.f;
            #pragma unroll
            for (int bb = 0; bb < NB; bb++) a += wc[bb] * basis1[(bb * D + i) * D + o];
            v[e] = (short)f2bf(a);
        }
        *((short8*)W1b + idx) = v;
    }
}

__global__ __launch_bounds__(1024) void k_scan1(const int* __restrict__ cnt2,
                                                int* __restrict__ boff2,
                                                int* __restrict__ bsum) {
    __shared__ int ws[16];
    int t = threadIdx.x, lane = t & 63, wv = t >> 6;
    int i = blockIdx.x * 1024 + t;
    int v = (i < NBKT) ? cnt2[i] : 0;
    int inc = v;
    for (int dd = 1; dd < 64; dd <<= 1) {
        int u = __shfl_up(inc, dd);
        if (lane >= dd) inc += u;
    }
    if (lane == 63) ws[wv] = inc;
    __syncthreads();
    if (t == 0) { int a = 0; for (int j = 0; j < 16; j++) { int x = ws[j]; ws[j] = a; a += x; } }
    __syncthreads();
    int ex = ws[wv] + inc - v;
    if (i < NBKT) boff2[i] = ex;
    if (t == 1023) bsum[blockIdx.x] = ex + v;
}

__global__ __launch_bounds__(1024) void k_scan2(int* __restrict__ bsum) {
    __shared__ int ws[16];
    int t = threadIdx.x, lane = t & 63, wv = t >> 6;
    int v = (t < NSB) ? bsum[t] : 0;
    int inc = v;
    for (int dd = 1; dd < 64; dd <<= 1) {
        int u = __shfl_up(inc, dd);
        if (lane >= dd) inc += u;
    }
    if (lane == 63) ws[wv] = inc;
    __syncthreads();
    if (t == 0) { int a = 0; for (int j = 0; j < 16; j++) { int x = ws[j]; ws[j] = a; a += x; } }
    __syncthreads();
    if (t < NSB) bsum[t] = ws[wv] + inc - v;
}

__global__ __launch_bounds__(1024) void k_scan3(int* __restrict__ boff2,
                                                const int* __restrict__ bsum,
                                                int* __restrict__ gcur2) {
    int i = blockIdx.x * 1024 + threadIdx.x;
    if (i < NBKT) {
        int f = boff2[i] + bsum[i >> 10];
        boff2[i] = f;
        gcur2[i] = f;
    }
    if (i == 0) boff2[NBKT] = NE;
}

// Fused scatter+h1, role-split:
//   blocks 0..781   : counting-sort scatter only
//   blocks 782..1563: h1 compute only (tile = b - 782)
__global__ __launch_bounds__(1024) void k_sh(
        const int* __restrict__ src, const int* __restrict__ dst,
        const int* __restrict__ et, int* __restrict__ gcur2,
        unsigned short* __restrict__ epack,
        const int* __restrict__ cnt2, const float* __restrict__ W0,
        const float* __restrict__ bias0, unsigned short* __restrict__ h1b) {
    int b = blockIdx.x, t = threadIdx.x;
    if (b < NT) {
        int i = b * 1024 + t;
        if (i < NE) {
            int d = dst[i];
            int key = (d >> 6) * 1280 + et[i] * 64 + (d & 63);
            int pos = atomicAdd(&gcur2[key], 1);
            epack[pos] = (unsigned short)src[i];
        }
        return;
    }
    __shared__ float cs[NR * 64];
    __shared__ float w0s[NR * D];
    int tile = b - NT;
    for (int j = t; j < NR * 64; j += 1024) cs[j] = (float)cnt2[tile * 1280 + j];
    for (int j = t; j < NR * D; j += 1024) w0s[j] = W0[j];
    __syncthreads();
    int nl = t >> 4, cg = t & 15;              // node-local, col-group of 8
    int n = tile * 64 + nl;
    if (n < NN) {
        float a[8];
        #pragma unroll
        for (int j = 0; j < 8; j++) a[j] = bias0[cg * 8 + j];
        for (int r = 0; r < NR; r++) {
            float c = cs[r * 64 + nl];
            #pragma unroll
            for (int j = 0; j < 8; j++) a[j] += c * w0s[r * D + cg * 8 + j];
        }
        short8 o;
        #pragma unroll
        for (int j = 0; j < 8; j++) o[j] = (short)f2bf(fmaxf(a[j], 0.f));
        *((short8*)(h1b + n * D + cg * 8)) = o;
    }
}

// Mega v12 (r15-proven, 94.3 us profiled): r13 body + epk/ooffs in LDS.
// 512 thr / 64-dst tile; wave wv owns output cols wv*16..+15 for all 64 rows.
// Per rel: 4 B-frag register loads (reused 4x) at rel-top; stage 64 rows ->
// Raw (node ids from LDS epk); reduce own bucket; publish swizzled Sl;
// 16 MFMA. 2 barriers/rel. No pipelining, no setprio (r16 showed both hurt).
__global__ __launch_bounds__(512, 2) void k_mega(
        const unsigned short* __restrict__ epack, const int* __restrict__ boff2,
        const unsigned short* __restrict__ h1b,
        const unsigned short* __restrict__ W1b,
        const unsigned short* __restrict__ linWb,
        const float* __restrict__ bias1, const float* __restrict__ lin_b,
        float* __restrict__ out) {
    __shared__ __align__(16) char lds[17408 + 16384];  // Raw 64x17s8 | Sl 64x16s8
    __shared__ unsigned short ooffs[1282];             // tile-relative offsets
    __shared__ unsigned short epk[2048];               // tile's src ids

    short8* Raw8 = (short8*)lds;
    short8* Sl8  = (short8*)(lds + 17408);

    int t = threadIdx.x, tile = blockIdx.x;
    int wv = t >> 6, lane = t & 63;
    int le = t >> 3, lp = t & 7;             // stage role: edge row, 16B pair
    int dl = t >> 3, cg = t & 7;             // reduce role: dst-local, col-group
    int row = lane & 15, gg = lane >> 4;     // mfma role

    int kbase = tile * 1280;
    int tb = boff2[kbase];
    for (int i = t; i < 1281; i += 512)
        ooffs[i] = (unsigned short)(boff2[kbase + i] - tb);
    __syncthreads();
    int nE = min((int)ooffs[1280], 2048);
    for (int i = t; i < nE; i += 512) epk[i] = epack[tb + i];
    __syncthreads();

    f32x4 acc[4];
    #pragma unroll
    for (int j = 0; j < 4; j++) acc[j] = (f32x4){0.f, 0.f, 0.f, 0.f};

    for (int r = 0; r < NR; r++) {
        int rbase = ooffs[r * 64];
        int cnt = ooffs[r * 64 + 64] - rbase;    // block-uniform
        if (cnt == 0) continue;

        const short8* Wg8 = (const short8*)W1b + r * 2048;
        short8 breg[4];
        #pragma unroll
        for (int kc = 0; kc < 4; kc++) breg[kc] = Wg8[(kc * 8 + wv) * 64 + lane];

        float s[16];
        #pragma unroll
        for (int k = 0; k < 16; k++) s[k] = 0.f;
        int o0 = ooffs[r * 64 + dl] - rbase;
        int o1 = ooffs[r * 64 + dl + 1] - rbase;
        int nc = (cnt + 63) >> 6;

        for (int c = 0; c < nc; c++) {
            int cb0 = c * 64, m = min(64, cnt - cb0);
            if (c > 0) __syncthreads();          // prev reduce done, Raw reusable
            if (le < m) {
                int node = epk[rbase + cb0 + le];
                const short8* hp = (const short8*)(h1b + (size_t)node * D) + lp * 2;
                Raw8[le * 17 + lp * 2]     = hp[0];
                Raw8[le * 17 + lp * 2 + 1] = hp[1];
            }
            __syncthreads();                     // Raw visible
            int lo = max(o0 - cb0, 0), hi = min(o1 - cb0, m);
            for (int p = lo; p < hi; p++) {
                short8 w0 = Raw8[p * 17 + 2 * cg];
                short8 w1 = Raw8[p * 17 + 2 * cg + 1];
                #pragma unroll
                for (int k = 0; k < 8; k++) {
                    s[k]     += bf2f((unsigned short)w0[k]);
                    s[8 + k] += bf2f((unsigned short)w1[k]);
                }
            }
        }
        short8 p0, p1;
        #pragma unroll
        for (int k = 0; k < 8; k++) {
            p0[k] = (short)f2bf(s[k]);
            p1[k] = (short)f2bf(s[8 + k]);
        }
        Sl8[dl * 16 + ((cg * 2)     ^ (dl & 15))] = p0;
        Sl8[dl * 16 + ((cg * 2 + 1) ^ (dl & 15))] = p1;
        __syncthreads();                         // Sl visible (all reduces done)
        #pragma unroll
        for (int rb = 0; rb < 4; rb++) {
            int arow = rb * 16 + row;
            #pragma unroll
            for (int kc = 0; kc < 4; kc++) {
                short8 a = Sl8[arow * 16 + ((kc * 4 + gg) ^ (arow & 15))];
                acc[rb] = __builtin_amdgcn_mfma_f32_16x16x32_bf16(a, breg[kc], acc[rb], 0, 0, 0);
            }
        }
    }

    __syncthreads();                             // last-rel Sl reads done
    // epilogue part 1: bias + relu -> bf16 Af[64][136] (aliases Raw region)
    unsigned short* Af = (unsigned short*)lds;
    #pragma unroll
    for (int rb = 0; rb < 4; rb++) {
        #pragma unroll
        for (int reg = 0; reg < 4; reg++) {
            int rr = rb * 16 + gg * 4 + reg;
            int col = wv * 16 + row;
            Af[rr * 136 + col] = f2bf(fmaxf(acc[rb][reg] + bias1[col], 0.f));
        }
    }
    __syncthreads();
    // epilogue part 2: out[64x64] = Af @ lin_w + lin_b via MFMA
    {
        int rb = wv & 3;
        int nt0 = (wv >> 2) * 2, nt1 = nt0 + 1;
        f32x4 ao0 = (f32x4){0.f, 0.f, 0.f, 0.f};
        f32x4 ao1 = (f32x4){0.f, 0.f, 0.f, 0.f};
        #pragma unroll
        for (int kc = 0; kc < 4; kc++) {
            short8 a = *(const short8*)(Af + (rb * 16 + row) * 136 + kc * 32 + gg * 8);
            short8 b0 = *((const short8*)linWb + (kc * 4 + nt0) * 64 + lane);
            short8 b1 = *((const short8*)linWb + (kc * 4 + nt1) * 64 + lane);
            ao0 = __builtin_amdgcn_mfma_f32_16x16x32_bf16(a, b0, ao0, 0, 0, 0);
            ao1 = __builtin_amdgcn_mfma_f32_16x16x32_bf16(a, b1, ao1, 0, 0, 0);
        }
        float lb0 = lin_b[nt0 * 16 + row];
        float lb1 = lin_b[nt1 * 16 + row];
        #pragma unroll
        for (int reg = 0; reg < 4; reg++) {
            int d = tile * 64 + rb * 16 + gg * 4 + reg;
            if (d < NN) {
                out[d * DO + nt0 * 16 + row] = ao0[reg] + lb0;
                out[d * DO + nt1 * 16 + row] = ao1[reg] + lb1;
            }
        }
    }
}

extern "C" void kernel_launch(void* const* d_in, const int* in_sizes, int n_in,
                              void* d_out, int out_size, void* d_ws, size_t ws_size,
                              hipStream_t stream) {
    const int*   src    = (const int*)d_in[0];
    const int*   dst    = (const int*)d_in[1];
    const int*   et     = (const int*)d_in[2];
    const float* basis0 = (const float*)d_in[4];
    const float* wcomp0 = (const float*)d_in[5];
    const float* bias0  = (const float*)d_in[6];
    const float* basis1 = (const float*)d_in[7];
    const float* wcomp1 = (const float*)d_in[8];
    const float* bias1  = (const float*)d_in[9];
    const float* lin_w  = (const float*)d_in[10];
    const float* lin_b  = (const float*)d_in[11];
    float* out = (float*)d_out;

    char* ws = (char*)d_ws;
    int*            cnt2    = (int*)           (ws + 0);
    int*            bsum    = (int*)           (ws + 4003840);
    int*            boff2   = (int*)           (ws + 4007808);
    int*            gcur2   = (int*)           (ws + 8011712);
    float*          W0      = (float*)         (ws + 12015616);
    unsigned short* W1b     = (unsigned short*)(ws + 12025856);
    unsigned short* h1b     = (unsigned short*)(ws + 12681216);
    unsigned short* epack   = (unsigned short*)(ws + 25481216);
    unsigned short* linWb   = (unsigned short*)(ws + 28681216);

    hipMemsetAsync(ws, 0, 4003840, stream);   // zero cnt2

    k_wh<<<NT + 40, 1024, 0, stream>>>(dst, et, basis0, wcomp0, basis1, wcomp1,
                                       lin_w, cnt2, W0, W1b, linWb);
    k_scan1<<<NSB, 1024, 0, stream>>>(cnt2, boff2, bsum);
    k_scan2<<<1, 1024, 0, stream>>>(bsum);
    k_scan3<<<NSB, 1024, 0, stream>>>(boff2, bsum, gcur2);
    k_sh<<<NT * 2, 1024, 0, stream>>>(src, dst, et, gcur2, epack,
                                      cnt2, W0, bias0, h1b);
    k_mega<<<NT, 512, 0, stream>>>(epack, boff2, h1b, W1b, linWb,
                                   bias1, lin_b, out);
}